// Round 3
// baseline (501.985 us; speedup 1.0000x reference)
//
#include <hip/hip_runtime.h>
#include <hip/hip_fp16.h>

#define IN_FEAT 128
#define HEADS 8
#define OUT_FEAT 16
#define HF 128  // HEADS*OUT_FEAT

// ---------------- K1: h = feat @ W_fc (fp16 out) and post[n][k][h] (fp32) ----
__global__ __launch_bounds__(256) void gemm_post_kernel(
    const float* __restrict__ feat, const float* __restrict__ W_fc,
    const float* __restrict__ W_post, const float* __restrict__ b_post,
    __half* __restrict__ hbuf, float* __restrict__ post, int N)
{
    __shared__ float4 lds4[32 * 32];          // 32 nodes x 128 feats (16 KB)
    float* lds = (float*)lds4;
    const int tid = threadIdx.x;
    const int node_base = blockIdx.x * 32;

    const float4* f4 = (const float4*)feat;
    for (int i = tid; i < 32 * 32; i += 256) {
        int n = i >> 5, k4 = i & 31;
        int gn = node_base + n;
        float4 v = make_float4(0.f, 0.f, 0.f, 0.f);
        if (gn < N) v = f4[gn * 32 + k4];
        lds4[i] = v;
    }
    __syncthreads();

    const int cg = tid & 31, ng = tid >> 5;
    const int n0 = ng * 4;
    float acc[4][4];
#pragma unroll
    for (int i = 0; i < 4; i++) acc[i][0] = acc[i][1] = acc[i][2] = acc[i][3] = 0.f;

    const float4* W4 = (const float4*)W_fc;
#pragma unroll 4
    for (int k = 0; k < 128; ++k) {
        float4 w = W4[k * 32 + cg];
#pragma unroll
        for (int i = 0; i < 4; i++) {
            float f = lds[(n0 + i) * 128 + k];
            acc[i][0] += f * w.x; acc[i][1] += f * w.y;
            acc[i][2] += f * w.z; acc[i][3] += f * w.w;
        }
    }
    __half2* hb2 = (__half2*)hbuf;
#pragma unroll
    for (int i = 0; i < 4; i++) {
        int gn = node_base + n0 + i;
        if (gn < N) {
            union { uint2 u; __half2 h[2]; } pk;
            pk.h[0] = __floats2half2_rn(acc[i][0], acc[i][1]);
            pk.h[1] = __floats2half2_rn(acc[i][2], acc[i][3]);
            *(uint2*)&hb2[gn * 64 + cg * 2] = pk.u;
        }
    }
    __syncthreads();
#pragma unroll
    for (int i = 0; i < 4; i++)
        lds4[(n0 + i) * 32 + cg] = make_float4(acc[i][0], acc[i][1], acc[i][2], acc[i][3]);
    __syncthreads();

    {
        int n = tid >> 3, h = tid & 7;
        float p0 = b_post[0], p1 = b_post[1], p2 = b_post[2], p3 = b_post[3];
#pragma unroll
        for (int f = 0; f < 16; ++f) {
            float v = lds[n * 128 + h * 16 + f];
            p0 += v * W_post[f * 4 + 0];
            p1 += v * W_post[f * 4 + 1];
            p2 += v * W_post[f * 4 + 2];
            p3 += v * W_post[f * 4 + 3];
        }
        int gn = node_base + n;
        if (gn < N) {
            // layout post[n][k][h], k: 0=loc_l 1=loc_r 2=lsl 3=lsr
            post[gn * 32 + 0 * 8 + h] = p0;
            post[gn * 32 + 1 * 8 + h] = p1;
            post[gn * 32 + 2 * 8 + h] = p2;
            post[gn * 32 + 3 * 8 + h] = p3;
        }
    }
}

// ---------------- K2: histogram of dst ----------------
__global__ __launch_bounds__(256) void hist_kernel(const int* __restrict__ dst,
                                                   int* __restrict__ counts, int E)
{
    int g = blockIdx.x * 256 + threadIdx.x;
    if (g < E) atomicAdd(&counts[dst[g]], 1);
}

// ---------------- K3a: per-256-chunk sums ----------------
__global__ __launch_bounds__(256) void block_sum_kernel(const int* __restrict__ counts,
                                                        int* __restrict__ blockSums, int N)
{
    __shared__ int sd[256];
    int tid = threadIdx.x;
    int g = blockIdx.x * 256 + tid;
    sd[tid] = (g < N) ? counts[g] : 0;
    __syncthreads();
    for (int off = 128; off > 0; off >>= 1) {
        if (tid < off) sd[tid] += sd[tid + off];
        __syncthreads();
    }
    if (tid == 0) blockSums[blockIdx.x] = sd[0];
}

// ---------------- K3b: exclusive scan of block sums (single block) ----------------
__global__ __launch_bounds__(256) void scan_sums_kernel(const int* __restrict__ blockSums,
                                                        int* __restrict__ blockOffs, int nb)
{
    __shared__ int sd[256];
    int tid = threadIdx.x;
    int v = (tid < nb) ? blockSums[tid] : 0;
    sd[tid] = v;
    __syncthreads();
    for (int off = 1; off < 256; off <<= 1) {
        int t = (tid >= off) ? sd[tid - off] : 0;
        __syncthreads();
        sd[tid] += t;
        __syncthreads();
    }
    if (tid < nb) blockOffs[tid] = sd[tid] - v;
}

// ---------------- K3c: per-chunk exclusive scan -> offsets, cursor ----------------
__global__ __launch_bounds__(256) void scan_block_kernel(
    const int* __restrict__ counts, const int* __restrict__ blockOffs,
    int* __restrict__ offsets, int* __restrict__ cursor, int N, int E)
{
    __shared__ int sd[256];
    int tid = threadIdx.x;
    int g = blockIdx.x * 256 + tid;
    int v = (g < N) ? counts[g] : 0;
    sd[tid] = v;
    __syncthreads();
    for (int off = 1; off < 256; off <<= 1) {
        int t = (tid >= off) ? sd[tid - off] : 0;
        __syncthreads();
        sd[tid] += t;
        __syncthreads();
    }
    if (g < N) {
        int o = blockOffs[blockIdx.x] + sd[tid] - v;
        offsets[g] = o;
        cursor[g] = o;
    }
    if (g == N) offsets[N] = E;
}

// ---------------- K4: scatter (src, edge) records into CSR order ----------------
__global__ __launch_bounds__(256) void scatter_kernel(const int* __restrict__ src,
                                                      const int* __restrict__ dst,
                                                      int* __restrict__ cursor,
                                                      int2* __restrict__ perm2, int E)
{
    int g = blockIdx.x * 256 + threadIdx.x;
    if (g < E) {
        int d = dst[g];
        int pos = atomicAdd(&cursor[d], 1);
        perm2[pos] = make_int2(src[g], g);
    }
}

// ---------------- K5: edge scores in edge order (fully coalesced) ----------------
__global__ __launch_bounds__(256) void score_kernel(
    const int* __restrict__ src, const int* __restrict__ dst,
    const float* __restrict__ eps, const float* __restrict__ post,
    __half* __restrict__ exbuf, int E)
{
    int e = blockIdx.x * 256 + threadIdx.x;
    if (e >= E) return;
    int s = src[e], d = dst[e];
    const float4* p4 = (const float4*)post;   // post row = 8 float4
    float4 ll0 = p4[s * 8 + 0], ll1 = p4[s * 8 + 1];   // loc_l[0..7]
    float4 sl0 = p4[s * 8 + 4], sl1 = p4[s * 8 + 5];   // lsl[0..7]
    float4 lr0 = p4[d * 8 + 2], lr1 = p4[d * 8 + 3];   // loc_r[0..7]
    float4 sr0 = p4[d * 8 + 6], sr1 = p4[d * 8 + 7];   // lsr[0..7]
    const float4* e4 = (const float4*)eps + (size_t)e * 2;
    float4 ep0 = e4[0], ep1 = e4[1];

    float ll[8] = {ll0.x, ll0.y, ll0.z, ll0.w, ll1.x, ll1.y, ll1.z, ll1.w};
    float sl[8] = {sl0.x, sl0.y, sl0.z, sl0.w, sl1.x, sl1.y, sl1.z, sl1.w};
    float lr[8] = {lr0.x, lr0.y, lr0.z, lr0.w, lr1.x, lr1.y, lr1.z, lr1.w};
    float sr[8] = {sr0.x, sr0.y, sr0.z, sr0.w, sr1.x, sr1.y, sr1.z, sr1.w};
    float ep[8] = {ep0.x, ep0.y, ep0.z, ep0.w, ep1.x, ep1.y, ep1.z, ep1.w};

    union { float4 f4; __half2 h2[4]; } pk;
#pragma unroll
    for (int h = 0; h < 4; ++h) {
        float ev0 = (ll[2*h] + lr[2*h]) + __expf(sl[2*h] + sr[2*h]) * ep[2*h];
        float ev1 = (ll[2*h+1] + lr[2*h+1]) + __expf(sl[2*h+1] + sr[2*h+1]) * ep[2*h+1];
        pk.h2[h] = __floats2half2_rn(__expf(ev0), __expf(ev1));
    }
    ((float4*)exbuf)[e] = pk.f4;
}

// ---------------- K6: per-node aggregation ----------------
// block = 128 = 2 waves, one dst node. lane -> (h = lane>>3, fp = lane&7);
// each lane accumulates feature pair (h*16+2fp, h*16+2fp+1) as float2.
// Wave w processes staged edges j = w, w+2, ... ; cross-wave reduce in LDS.
__global__ __launch_bounds__(128) void agg_kernel(
    const int2* __restrict__ perm2, const int* __restrict__ offsets,
    const __half* __restrict__ exbuf, const __half* __restrict__ hbuf,
    const float* __restrict__ bias, float* __restrict__ out)
{
    __shared__ int    s_src[32];
    __shared__ float  s_a[32 * 9];      // stride 9: conflict-free staging writes
    __shared__ float2 r_acc[64];
    __shared__ float  r_dsum[64];

    const int d = blockIdx.x;
    const int tid = threadIdx.x;
    const int wave = tid >> 6, lane = tid & 63;
    const int h = lane >> 3, fp = lane & 7;
    const int start = offsets[d];
    const int deg = offsets[d + 1] - start;

    float2 acc = make_float2(0.f, 0.f);
    float dsum = 0.f;

    for (int c = 0; c < deg; c += 32) {
        int jc = min(32, deg - c);
        if (tid < jc) {
            int2 pe = perm2[start + c + tid];
            s_src[tid] = pe.x;
            union { float4 f4; __half2 h2[4]; } u;
            u.f4 = ((const float4*)exbuf)[pe.y];
#pragma unroll
            for (int k = 0; k < 4; ++k) {
                float2 f = __half22float2(u.h2[k]);
                s_a[tid * 9 + 2 * k]     = f.x;
                s_a[tid * 9 + 2 * k + 1] = f.y;
            }
        }
        __syncthreads();
        for (int j = wave; j < jc; j += 2) {
            float a = s_a[j * 9 + h];
            const __half2* hr = (const __half2*)(hbuf + (size_t)s_src[j] * 128);
            float2 hv = __half22float2(hr[h * 8 + fp]);
            acc.x += a * hv.x;
            acc.y += a * hv.y;
            dsum  += a;
        }
        __syncthreads();
    }

    if (wave == 0) { r_acc[lane] = acc; r_dsum[lane] = dsum; }
    __syncthreads();
    if (wave == 1) {
        r_acc[lane].x += acc.x;
        r_acc[lane].y += acc.y;
        r_dsum[lane]  += dsum;
    }
    __syncthreads();
    if (wave == 0) {
        float2 A = r_acc[lane];
        float ds = r_dsum[lane];
        float inv = (ds > 0.f) ? 1.f / ds : 0.f;
        float2 o;
        o.x = A.x * inv + bias[h * 16 + 2 * fp];
        o.y = A.y * inv + bias[h * 16 + 2 * fp + 1];
        ((float2*)out)[(size_t)d * 64 + lane] = o;
    }
}

extern "C" void kernel_launch(void* const* d_in, const int* in_sizes, int n_in,
                              void* d_out, int out_size, void* d_ws, size_t ws_size,
                              hipStream_t stream)
{
    const float* feat   = (const float*)d_in[0];
    const int*   src    = (const int*)d_in[1];
    const int*   dst    = (const int*)d_in[2];
    const float* eps    = (const float*)d_in[3];
    const float* W_fc   = (const float*)d_in[4];
    const float* W_post = (const float*)d_in[5];
    const float* b_post = (const float*)d_in[6];
    const float* bias   = (const float*)d_in[7];
    float* out = (float*)d_out;

    const int N = in_sizes[0] / IN_FEAT;   // 50000
    const int E = in_sizes[1];             // 1600000

    // workspace layout (256B-aligned segments), total ~59 MB
    char* p = (char*)d_ws;
    auto alloc = [&](size_t bytes) {
        char* r = p;
        p += (bytes + 255) & ~size_t(255);
        return r;
    };
    __half* hbuf   = (__half*)alloc((size_t)N * HF * 2);      // 12.8 MB fp16
    float*  post   = (float*)alloc((size_t)N * 32 * 4);       // 6.4 MB
    int*    counts = (int*)alloc((size_t)N * 4);
    int*    offsets= (int*)alloc((size_t)(N + 1) * 4);
    int*    cursor = (int*)alloc((size_t)N * 4);
    int*    blockSums = (int*)alloc(1024);
    int*    blockOffs = (int*)alloc(1024);
    int2*   perm2  = (int2*)alloc((size_t)E * 8);             // 12.8 MB (src, edge)
    __half* exbuf  = (__half*)alloc((size_t)E * 8 * 2);       // 25.6 MB

    hipMemsetAsync(counts, 0, (size_t)N * 4, stream);

    const int nbScan = (N + 255) / 256;  // 196

    gemm_post_kernel<<<(N + 31) / 32, 256, 0, stream>>>(feat, W_fc, W_post, b_post,
                                                        hbuf, post, N);
    hist_kernel<<<(E + 255) / 256, 256, 0, stream>>>(dst, counts, E);
    block_sum_kernel<<<nbScan, 256, 0, stream>>>(counts, blockSums, N);
    scan_sums_kernel<<<1, 256, 0, stream>>>(blockSums, blockOffs, nbScan);
    scan_block_kernel<<<nbScan, 256, 0, stream>>>(counts, blockOffs, offsets, cursor, N, E);
    scatter_kernel<<<(E + 255) / 256, 256, 0, stream>>>(src, dst, cursor, perm2, E);
    score_kernel<<<(E + 255) / 256, 256, 0, stream>>>(src, dst, eps, post, exbuf, E);
    agg_kernel<<<N, 128, 0, stream>>>(perm2, offsets, exbuf, hbuf, bias, out);
}

// Round 4
// 411.349 us; speedup vs baseline: 1.2203x; 1.2203x over previous
//
#include <hip/hip_runtime.h>
#include <hip/hip_fp16.h>

#define IN_FEAT 128
#define HEADS 8
#define OUT_FEAT 16
#define HF 128      // HEADS*OUT_FEAT
#define CHUNK 4096  // edges per bucket_scatter block

// ---------------- K1: h = feat @ W_fc (fp16 out) and post[n][k][h] (fp32) ----
__global__ __launch_bounds__(256) void gemm_post_kernel(
    const float* __restrict__ feat, const float* __restrict__ W_fc,
    const float* __restrict__ W_post, const float* __restrict__ b_post,
    __half* __restrict__ hbuf, float* __restrict__ post, int N)
{
    __shared__ float4 lds4[32 * 32];          // 32 nodes x 128 feats (16 KB)
    float* lds = (float*)lds4;
    const int tid = threadIdx.x;
    const int node_base = blockIdx.x * 32;

    const float4* f4 = (const float4*)feat;
    for (int i = tid; i < 32 * 32; i += 256) {
        int n = i >> 5, k4 = i & 31;
        int gn = node_base + n;
        float4 v = make_float4(0.f, 0.f, 0.f, 0.f);
        if (gn < N) v = f4[gn * 32 + k4];
        lds4[i] = v;
    }
    __syncthreads();

    const int cg = tid & 31, ng = tid >> 5;
    const int n0 = ng * 4;
    float acc[4][4];
#pragma unroll
    for (int i = 0; i < 4; i++) acc[i][0] = acc[i][1] = acc[i][2] = acc[i][3] = 0.f;

    const float4* W4 = (const float4*)W_fc;
#pragma unroll 4
    for (int k = 0; k < 128; ++k) {
        float4 w = W4[k * 32 + cg];
#pragma unroll
        for (int i = 0; i < 4; i++) {
            float f = lds[(n0 + i) * 128 + k];
            acc[i][0] += f * w.x; acc[i][1] += f * w.y;
            acc[i][2] += f * w.z; acc[i][3] += f * w.w;
        }
    }
    __half2* hb2 = (__half2*)hbuf;
#pragma unroll
    for (int i = 0; i < 4; i++) {
        int gn = node_base + n0 + i;
        if (gn < N) {
            union { uint2 u; __half2 h[2]; } pk;
            pk.h[0] = __floats2half2_rn(acc[i][0], acc[i][1]);
            pk.h[1] = __floats2half2_rn(acc[i][2], acc[i][3]);
            *(uint2*)&hb2[gn * 64 + cg * 2] = pk.u;
        }
    }
    __syncthreads();
#pragma unroll
    for (int i = 0; i < 4; i++)
        lds4[(n0 + i) * 32 + cg] = make_float4(acc[i][0], acc[i][1], acc[i][2], acc[i][3]);
    __syncthreads();

    {
        int n = tid >> 3, h = tid & 7;
        float p0 = b_post[0], p1 = b_post[1], p2 = b_post[2], p3 = b_post[3];
#pragma unroll
        for (int f = 0; f < 16; ++f) {
            float v = lds[n * 128 + h * 16 + f];
            p0 += v * W_post[f * 4 + 0];
            p1 += v * W_post[f * 4 + 1];
            p2 += v * W_post[f * 4 + 2];
            p3 += v * W_post[f * 4 + 3];
        }
        int gn = node_base + n;
        if (gn < N) {
            // layout post[n][k][h], k: 0=loc_l 1=loc_r 2=lsl 3=lsr
            post[gn * 32 + 0 * 8 + h] = p0;
            post[gn * 32 + 1 * 8 + h] = p1;
            post[gn * 32 + 2 * 8 + h] = p2;
            post[gn * 32 + 3 * 8 + h] = p3;
        }
    }
}

// ---------------- K2: bucket histogram (bucket = dst>>8) ----------------
__global__ __launch_bounds__(256) void bucket_hist_kernel(
    const int* __restrict__ dst, int* __restrict__ bucket_tot, int E)
{
    __shared__ int cnt[256];
    const int tid = threadIdx.x;
    cnt[tid] = 0;
    __syncthreads();
    const int stride = gridDim.x * 256;
    for (int g = blockIdx.x * 256 + tid; g < E; g += stride)
        atomicAdd(&cnt[dst[g] >> 8], 1);
    __syncthreads();
    int c = cnt[tid];
    if (c) atomicAdd(&bucket_tot[tid], c);
}

// ---------------- K3: scan bucket totals -> base, cursor ----------------
__global__ __launch_bounds__(256) void bucket_scan_kernel(
    const int* __restrict__ bucket_tot, int* __restrict__ bucket_base,
    int* __restrict__ bucket_cursor, int nb, int E)
{
    __shared__ int sd[256];
    const int tid = threadIdx.x;
    int v = (tid < nb) ? bucket_tot[tid] : 0;
    sd[tid] = v;
    __syncthreads();
    for (int off = 1; off < 256; off <<= 1) {
        int t = (tid >= off) ? sd[tid - off] : 0;
        __syncthreads();
        sd[tid] += t;
        __syncthreads();
    }
    int excl = sd[tid] - v;
    if (tid < nb) { bucket_base[tid] = excl; bucket_cursor[tid] = excl; }
    if (tid == nb) bucket_base[nb] = E;
}

// ---------------- K4: bin edges into bucket-contiguous record arrays --------
// Each block owns CHUNK consecutive edges; reserves per-bucket ranges with ONE
// atomic per bucket, then writes its records into its private sub-ranges
// (single-CU writer -> lines coalesce in that XCD's L2).
__global__ __launch_bounds__(256) void bucket_scatter_kernel(
    const int* __restrict__ src, const int* __restrict__ dst,
    int* __restrict__ bucket_cursor, uint2* __restrict__ recs, int E)
{
    __shared__ int cnt[256];
    __shared__ int base[256];
    const int tid = threadIdx.x;
    cnt[tid] = 0;
    __syncthreads();
    const int e0 = blockIdx.x * CHUNK;
    const int e1 = min(e0 + CHUNK, E);
    for (int e = e0 + tid; e < e1; e += 256)
        atomicAdd(&cnt[dst[e] >> 8], 1);
    __syncthreads();
    int c = cnt[tid];
    base[tid] = c ? atomicAdd(&bucket_cursor[tid], c) : 0;
    cnt[tid] = 0;   // reuse as local cursor
    __syncthreads();
    for (int e = e0 + tid; e < e1; e += 256) {
        int d = dst[e];
        int b = d >> 8;
        int slot = base[b] + atomicAdd(&cnt[b], 1);
        recs[slot] = make_uint2((unsigned)e,
                                ((unsigned)src[e] << 8) | (unsigned)(d & 255));
    }
}

// ---------------- K5: per-bucket CSR build + edge scores ----------------
// One block per bucket. Local node hist -> LDS scan -> global offsets; then
// compute ex[8] per record (dst-side post rows preloaded in LDS) and write
// perm[slot]=src, ex_csr[slot] (fp16x8). All scattered writes confined to this
// bucket's region, written only by this block.
__global__ __launch_bounds__(256) void bucket_csr_kernel(
    const uint2* __restrict__ recs, const int* __restrict__ bucket_base,
    const float* __restrict__ post, const float* __restrict__ eps,
    int* __restrict__ offsets, int* __restrict__ perm, __half* __restrict__ excsr,
    int N, int E, int nb)
{
    __shared__ int ncnt[256];
    __shared__ int snc[256];
    __shared__ float4 drow[256 * 4];   // per-node: lr0 lr1 sr0 sr1 (16 KB)
    const int b = blockIdx.x, tid = threadIdx.x;
    const int node_lo = b << 8;
    const int rlo = bucket_base[b], rhi = bucket_base[b + 1];
    const int gn = node_lo + tid;
    const float4* p4 = (const float4*)post;

    ncnt[tid] = 0;
    if (gn < N) {
        drow[tid * 4 + 0] = p4[gn * 8 + 2];
        drow[tid * 4 + 1] = p4[gn * 8 + 3];
        drow[tid * 4 + 2] = p4[gn * 8 + 6];
        drow[tid * 4 + 3] = p4[gn * 8 + 7];
    }
    __syncthreads();
    for (int r = rlo + tid; r < rhi; r += 256)
        atomicAdd(&ncnt[recs[r].y & 255u], 1);
    __syncthreads();
    int v = ncnt[tid];
    snc[tid] = v;
    __syncthreads();
    for (int off = 1; off < 256; off <<= 1) {
        int t = (tid >= off) ? snc[tid - off] : 0;
        __syncthreads();
        snc[tid] += t;
        __syncthreads();
    }
    int excl = snc[tid] - v;
    if (gn < N) offsets[gn] = rlo + excl;
    if (b == 0 && tid == 0) offsets[N] = E;
    __syncthreads();
    ncnt[tid] = excl;   // relative cursor
    __syncthreads();

    for (int r = rlo + tid; r < rhi; r += 256) {
        uint2 rec = recs[r];
        int e  = (int)rec.x;
        int s  = (int)(rec.y >> 8);
        int dl = (int)(rec.y & 255u);
        float4 ll0 = p4[s * 8 + 0], ll1 = p4[s * 8 + 1];
        float4 sl0 = p4[s * 8 + 4], sl1 = p4[s * 8 + 5];
        float4 lr0 = drow[dl * 4 + 0], lr1 = drow[dl * 4 + 1];
        float4 sr0 = drow[dl * 4 + 2], sr1 = drow[dl * 4 + 3];
        const float4* e4 = (const float4*)eps + (size_t)e * 2;
        float4 ep0 = e4[0], ep1 = e4[1];

        float ll[8] = {ll0.x, ll0.y, ll0.z, ll0.w, ll1.x, ll1.y, ll1.z, ll1.w};
        float sl[8] = {sl0.x, sl0.y, sl0.z, sl0.w, sl1.x, sl1.y, sl1.z, sl1.w};
        float lr[8] = {lr0.x, lr0.y, lr0.z, lr0.w, lr1.x, lr1.y, lr1.z, lr1.w};
        float sr[8] = {sr0.x, sr0.y, sr0.z, sr0.w, sr1.x, sr1.y, sr1.z, sr1.w};
        float ep[8] = {ep0.x, ep0.y, ep0.z, ep0.w, ep1.x, ep1.y, ep1.z, ep1.w};

        union { float4 f4; __half2 h2[4]; } pk;
#pragma unroll
        for (int h = 0; h < 4; ++h) {
            float ev0 = (ll[2*h]   + lr[2*h])   + __expf(sl[2*h]   + sr[2*h])   * ep[2*h];
            float ev1 = (ll[2*h+1] + lr[2*h+1]) + __expf(sl[2*h+1] + sr[2*h+1]) * ep[2*h+1];
            pk.h2[h] = __floats2half2_rn(__expf(ev0), __expf(ev1));
        }
        int slot = rlo + atomicAdd(&ncnt[dl], 1);
        perm[slot] = s;
        ((float4*)excsr)[slot] = pk.f4;
    }
}

// ---------------- K6: per-node aggregation ----------------
// block = 128 = 2 waves, one dst node. lane -> (h = lane>>3, fp = lane&7);
// each lane accumulates feature pair (h*16+2fp, h*16+2fp+1) as float2.
__global__ __launch_bounds__(128) void agg_kernel(
    const int* __restrict__ perm, const int* __restrict__ offsets,
    const __half* __restrict__ excsr, const __half* __restrict__ hbuf,
    const float* __restrict__ bias, float* __restrict__ out)
{
    __shared__ int    s_src[32];
    __shared__ float  s_a[32 * 9];      // stride 9: conflict-free staging writes
    __shared__ float2 r_acc[64];
    __shared__ float  r_dsum[64];

    const int d = blockIdx.x;
    const int tid = threadIdx.x;
    const int wave = tid >> 6, lane = tid & 63;
    const int h = lane >> 3, fp = lane & 7;
    const int start = offsets[d];
    const int deg = offsets[d + 1] - start;

    float2 acc = make_float2(0.f, 0.f);
    float dsum = 0.f;

    for (int c = 0; c < deg; c += 32) {
        int jc = min(32, deg - c);
        if (tid < jc) {
            s_src[tid] = perm[start + c + tid];
            union { float4 f4; __half2 h2[4]; } u;
            u.f4 = ((const float4*)excsr)[start + c + tid];   // coalesced
#pragma unroll
            for (int k = 0; k < 4; ++k) {
                float2 f = __half22float2(u.h2[k]);
                s_a[tid * 9 + 2 * k]     = f.x;
                s_a[tid * 9 + 2 * k + 1] = f.y;
            }
        }
        __syncthreads();
        for (int j = wave; j < jc; j += 2) {
            float a = s_a[j * 9 + h];
            const __half2* hr = (const __half2*)(hbuf + (size_t)s_src[j] * 128);
            float2 hv = __half22float2(hr[h * 8 + fp]);
            acc.x += a * hv.x;
            acc.y += a * hv.y;
            dsum  += a;
        }
        __syncthreads();
    }

    if (wave == 0) { r_acc[lane] = acc; r_dsum[lane] = dsum; }
    __syncthreads();
    if (wave == 1) {
        r_acc[lane].x += acc.x;
        r_acc[lane].y += acc.y;
        r_dsum[lane]  += dsum;
    }
    __syncthreads();
    if (wave == 0) {
        float2 A = r_acc[lane];
        float ds = r_dsum[lane];
        float inv = (ds > 0.f) ? 1.f / ds : 0.f;
        float2 o;
        o.x = A.x * inv + bias[h * 16 + 2 * fp];
        o.y = A.y * inv + bias[h * 16 + 2 * fp + 1];
        ((float2*)out)[(size_t)d * 64 + lane] = o;
    }
}

extern "C" void kernel_launch(void* const* d_in, const int* in_sizes, int n_in,
                              void* d_out, int out_size, void* d_ws, size_t ws_size,
                              hipStream_t stream)
{
    const float* feat   = (const float*)d_in[0];
    const int*   src    = (const int*)d_in[1];
    const int*   dst    = (const int*)d_in[2];
    const float* eps    = (const float*)d_in[3];
    const float* W_fc   = (const float*)d_in[4];
    const float* W_post = (const float*)d_in[5];
    const float* b_post = (const float*)d_in[6];
    const float* bias   = (const float*)d_in[7];
    float* out = (float*)d_out;

    const int N = in_sizes[0] / IN_FEAT;   // 50000
    const int E = in_sizes[1];             // 1600000
    const int nb = (N + 255) >> 8;         // 196 buckets

    // workspace layout (256B-aligned segments), total ~64.3 MB
    char* p = (char*)d_ws;
    auto alloc = [&](size_t bytes) {
        char* r = p;
        p += (bytes + 255) & ~size_t(255);
        return r;
    };
    __half* hbuf    = (__half*)alloc((size_t)N * HF * 2);     // 12.8 MB fp16
    float*  post    = (float*)alloc((size_t)N * 32 * 4);      // 6.4 MB
    int*    offsets = (int*)alloc((size_t)(N + 1) * 4);
    int*    bucket_tot    = (int*)alloc(1024);
    int*    bucket_base   = (int*)alloc(1024);
    int*    bucket_cursor = (int*)alloc(1024);
    uint2*  recs    = (uint2*)alloc((size_t)E * 8);           // 12.8 MB
    int*    perm    = (int*)alloc((size_t)E * 4);             // 6.4 MB (src)
    __half* excsr   = (__half*)alloc((size_t)E * 8 * 2);      // 25.6 MB

    hipMemsetAsync(bucket_tot, 0, 1024, stream);

    gemm_post_kernel<<<(N + 31) / 32, 256, 0, stream>>>(feat, W_fc, W_post, b_post,
                                                        hbuf, post, N);
    bucket_hist_kernel<<<512, 256, 0, stream>>>(dst, bucket_tot, E);
    bucket_scan_kernel<<<1, 256, 0, stream>>>(bucket_tot, bucket_base,
                                              bucket_cursor, nb, E);
    bucket_scatter_kernel<<<(E + CHUNK - 1) / CHUNK, 256, 0, stream>>>(
        src, dst, bucket_cursor, recs, E);
    bucket_csr_kernel<<<nb, 256, 0, stream>>>(recs, bucket_base, post, eps,
                                              offsets, perm, excsr, N, E, nb);
    agg_kernel<<<N, 128, 0, stream>>>(perm, offsets, excsr, hbuf, bias, out);
}

// Round 5
// 359.472 us; speedup vs baseline: 1.3964x; 1.1443x over previous
//
#include <hip/hip_runtime.h>
#include <hip/hip_fp16.h>

#define IN_FEAT 128
#define HEADS 8
#define OUT_FEAT 16
#define HF 128       // HEADS*OUT_FEAT
#define BSHIFT 6     // bucket = dst >> 6  (64 nodes/bucket)
#define BNODES 64
#define NBMAX 1024
#define CHUNK 8192   // edges per bucket_scatter block

// ---------------- K1: h = feat @ W_fc (fp16 out) and post[n][k][h] (fp32) ----
__global__ __launch_bounds__(256) void gemm_post_kernel(
    const float* __restrict__ feat, const float* __restrict__ W_fc,
    const float* __restrict__ W_post, const float* __restrict__ b_post,
    __half* __restrict__ hbuf, float* __restrict__ post, int N)
{
    __shared__ float4 lds4[32 * 32];          // 32 nodes x 128 feats (16 KB)
    float* lds = (float*)lds4;
    const int tid = threadIdx.x;
    const int node_base = blockIdx.x * 32;

    const float4* f4 = (const float4*)feat;
    for (int i = tid; i < 32 * 32; i += 256) {
        int n = i >> 5, k4 = i & 31;
        int gn = node_base + n;
        float4 v = make_float4(0.f, 0.f, 0.f, 0.f);
        if (gn < N) v = f4[gn * 32 + k4];
        lds4[i] = v;
    }
    __syncthreads();

    const int cg = tid & 31, ng = tid >> 5;
    const int n0 = ng * 4;
    float acc[4][4];
#pragma unroll
    for (int i = 0; i < 4; i++) acc[i][0] = acc[i][1] = acc[i][2] = acc[i][3] = 0.f;

    const float4* W4 = (const float4*)W_fc;
#pragma unroll 4
    for (int k = 0; k < 128; ++k) {
        float4 w = W4[k * 32 + cg];
#pragma unroll
        for (int i = 0; i < 4; i++) {
            float f = lds[(n0 + i) * 128 + k];
            acc[i][0] += f * w.x; acc[i][1] += f * w.y;
            acc[i][2] += f * w.z; acc[i][3] += f * w.w;
        }
    }
    __half2* hb2 = (__half2*)hbuf;
#pragma unroll
    for (int i = 0; i < 4; i++) {
        int gn = node_base + n0 + i;
        if (gn < N) {
            union { uint2 u; __half2 h[2]; } pk;
            pk.h[0] = __floats2half2_rn(acc[i][0], acc[i][1]);
            pk.h[1] = __floats2half2_rn(acc[i][2], acc[i][3]);
            *(uint2*)&hb2[gn * 64 + cg * 2] = pk.u;
        }
    }
    __syncthreads();
#pragma unroll
    for (int i = 0; i < 4; i++)
        lds4[(n0 + i) * 32 + cg] = make_float4(acc[i][0], acc[i][1], acc[i][2], acc[i][3]);
    __syncthreads();

    {
        int n = tid >> 3, h = tid & 7;
        float p0 = b_post[0], p1 = b_post[1], p2 = b_post[2], p3 = b_post[3];
#pragma unroll
        for (int f = 0; f < 16; ++f) {
            float v = lds[n * 128 + h * 16 + f];
            p0 += v * W_post[f * 4 + 0];
            p1 += v * W_post[f * 4 + 1];
            p2 += v * W_post[f * 4 + 2];
            p3 += v * W_post[f * 4 + 3];
        }
        int gn = node_base + n;
        if (gn < N) {
            // layout post[n][k][h], k: 0=loc_l 1=loc_r 2=lsl 3=lsr
            post[gn * 32 + 0 * 8 + h] = p0;
            post[gn * 32 + 1 * 8 + h] = p1;
            post[gn * 32 + 2 * 8 + h] = p2;
            post[gn * 32 + 3 * 8 + h] = p3;
        }
    }
}

// ---------------- K2: bucket histogram (bucket = dst>>6) ----------------
__global__ __launch_bounds__(256) void bucket_hist_kernel(
    const int* __restrict__ dst, int* __restrict__ bucket_tot, int E, int nb)
{
    __shared__ int cnt[NBMAX];
    const int tid = threadIdx.x;
    for (int i = tid; i < nb; i += 256) cnt[i] = 0;
    __syncthreads();
    const int stride = gridDim.x * 256;
    for (int g = blockIdx.x * 256 + tid; g < E; g += stride)
        atomicAdd(&cnt[dst[g] >> BSHIFT], 1);
    __syncthreads();
    for (int i = tid; i < nb; i += 256) {
        int c = cnt[i];
        if (c) atomicAdd(&bucket_tot[i], c);
    }
}

// ---------------- K3: scan bucket totals -> base, cursor ----------------
__global__ __launch_bounds__(256) void bucket_scan_kernel(
    const int* __restrict__ bucket_tot, int* __restrict__ bucket_base,
    int* __restrict__ bucket_cursor, int nb, int E)
{
    __shared__ int sd[256];
    const int tid = threadIdx.x;
    int v[4]; int s = 0;
#pragma unroll
    for (int k = 0; k < 4; ++k) {
        int i = tid * 4 + k;
        v[k] = (i < nb) ? bucket_tot[i] : 0;
        s += v[k];
    }
    sd[tid] = s;
    __syncthreads();
    for (int off = 1; off < 256; off <<= 1) {
        int t = (tid >= off) ? sd[tid - off] : 0;
        __syncthreads();
        sd[tid] += t;
        __syncthreads();
    }
    int excl = sd[tid] - s;
#pragma unroll
    for (int k = 0; k < 4; ++k) {
        int i = tid * 4 + k;
        if (i < nb) { bucket_base[i] = excl; bucket_cursor[i] = excl; }
        excl += v[k];
    }
    if (tid == 0) bucket_base[nb] = E;
}

// ---------------- K4: bin edges into bucket-contiguous record arrays --------
__global__ __launch_bounds__(256) void bucket_scatter_kernel(
    const int* __restrict__ src, const int* __restrict__ dst,
    int* __restrict__ bucket_cursor, uint2* __restrict__ recs, int E, int nb)
{
    __shared__ int cnt[NBMAX];
    __shared__ int base[NBMAX];
    const int tid = threadIdx.x;
    for (int i = tid; i < nb; i += 256) cnt[i] = 0;
    __syncthreads();
    const int e0 = blockIdx.x * CHUNK;
    const int e1 = min(e0 + CHUNK, E);
    for (int e = e0 + tid; e < e1; e += 256)
        atomicAdd(&cnt[dst[e] >> BSHIFT], 1);
    __syncthreads();
    for (int i = tid; i < nb; i += 256) {
        int c = cnt[i];
        base[i] = c ? atomicAdd(&bucket_cursor[i], c) : 0;
        cnt[i] = 0;   // reuse as local cursor
    }
    __syncthreads();
    for (int e = e0 + tid; e < e1; e += 256) {
        int d = dst[e];
        int b = d >> BSHIFT;
        int slot = base[b] + atomicAdd(&cnt[b], 1);
        recs[slot] = make_uint2((unsigned)e,
                                ((unsigned)src[e] << BSHIFT) | (unsigned)(d & (BNODES - 1)));
    }
}

// ---------------- K5: per-bucket CSR build (records -> slot order) ----------
// One block per bucket (64 nodes). Pure streaming: local node hist -> scan ->
// offsets; then csr[slot] = (edge, src). Single-writer bucket region.
__global__ __launch_bounds__(256) void bucket_csr_kernel(
    const uint2* __restrict__ recs, const int* __restrict__ bucket_base,
    int* __restrict__ offsets, uint2* __restrict__ csr, int N, int E)
{
    __shared__ int ncnt[BNODES];
    __shared__ int snc[BNODES];
    const int b = blockIdx.x, tid = threadIdx.x;
    const int node_lo = b << BSHIFT;
    const int rlo = bucket_base[b], rhi = bucket_base[b + 1];
    const int gn = node_lo + tid;

    if (tid < BNODES) ncnt[tid] = 0;
    __syncthreads();
    for (int r = rlo + tid; r < rhi; r += 256)
        atomicAdd(&ncnt[recs[r].y & (BNODES - 1u)], 1);
    __syncthreads();
    if (tid < BNODES) snc[tid] = ncnt[tid];
    __syncthreads();
    for (int off = 1; off < BNODES; off <<= 1) {
        int t = (tid < BNODES && tid >= off) ? snc[tid - off] : 0;
        __syncthreads();
        if (tid < BNODES) snc[tid] += t;
        __syncthreads();
    }
    int excl = (tid < BNODES) ? snc[tid] - ncnt[tid] : 0;
    if (tid < BNODES && gn < N) offsets[gn] = rlo + excl;
    if (b == 0 && tid == 0) offsets[N] = E;
    __syncthreads();
    if (tid < BNODES) ncnt[tid] = excl;   // relative cursor
    __syncthreads();

    for (int r = rlo + tid; r < rhi; r += 256) {
        uint2 rec = recs[r];
        int dl = (int)(rec.y & (BNODES - 1u));
        unsigned s = rec.y >> BSHIFT;
        int slot = rlo + atomicAdd(&ncnt[dl], 1);
        csr[slot] = make_uint2(rec.x, s);   // (edge, src)
    }
}

// ---------------- K6: fused score + aggregation ----------------
// block = 128 = 2 waves, one dst node. Staging: 4 threads per edge (quarter q
// handles heads 2q,2q+1) gather post[src] + eps[edge], compute ex, stash in
// LDS. Inner: lane -> (h = lane>>3, fp = lane&7) accumulates float2 of h-row.
__global__ __launch_bounds__(128) void agg_kernel(
    const uint2* __restrict__ csr, const int* __restrict__ offsets,
    const float* __restrict__ post, const float* __restrict__ eps,
    const __half* __restrict__ hbuf, const float* __restrict__ bias,
    float* __restrict__ out)
{
    __shared__ int    s_src[32];
    __shared__ float  s_a[32 * 9];      // stride 9: conflict-light
    __shared__ float  dpost[16];        // lr[0..7], sr[0..7]
    __shared__ float2 r_acc[64];
    __shared__ float  r_dsum[64];

    const int d = blockIdx.x;
    const int tid = threadIdx.x;
    const int wave = tid >> 6, lane = tid & 63;
    const int h = lane >> 3, fp = lane & 7;
    const int start = offsets[d];
    const int deg = offsets[d + 1] - start;

    if (tid < 16)
        dpost[tid] = post[d * 32 + ((tid < 8) ? (8 + tid) : (16 + tid))];
    __syncthreads();

    float2 acc = make_float2(0.f, 0.f);
    float dsum = 0.f;

    const float2* p2 = (const float2*)post;   // post row = 16 float2
    const float2* e2 = (const float2*)eps;    // eps row = 4 float2

    for (int c = 0; c < deg; c += 32) {
        int jc = min(32, deg - c);
        if (tid < 4 * jc) {
            int j = tid >> 2, q = tid & 3;
            uint2 rec = csr[start + c + j];
            int e = (int)rec.x, s = (int)rec.y;
            if (q == 0) s_src[j] = s;
            float2 ll = p2[(size_t)s * 16 + q];          // loc_l[2q,2q+1]
            float2 sl = p2[(size_t)s * 16 + 8 + q];      // lsl[2q,2q+1]
            float2 ep = e2[(size_t)e * 4 + q];
            int h0 = 2 * q;
            float ev0 = (ll.x + dpost[h0])     + __expf(sl.x + dpost[8 + h0])     * ep.x;
            float ev1 = (ll.y + dpost[h0 + 1]) + __expf(sl.y + dpost[8 + h0 + 1]) * ep.y;
            s_a[j * 9 + h0]     = __expf(ev0);
            s_a[j * 9 + h0 + 1] = __expf(ev1);
        }
        __syncthreads();
        for (int j = wave; j < jc; j += 2) {
            float a = s_a[j * 9 + h];
            const __half2* hr = (const __half2*)(hbuf + (size_t)s_src[j] * 128);
            float2 hv = __half22float2(hr[h * 8 + fp]);
            acc.x += a * hv.x;
            acc.y += a * hv.y;
            dsum  += a;
        }
        __syncthreads();
    }

    if (wave == 0) { r_acc[lane] = acc; r_dsum[lane] = dsum; }
    __syncthreads();
    if (wave == 1) {
        r_acc[lane].x += acc.x;
        r_acc[lane].y += acc.y;
        r_dsum[lane]  += dsum;
    }
    __syncthreads();
    if (wave == 0) {
        float2 A = r_acc[lane];
        float ds = r_dsum[lane];
        float inv = (ds > 0.f) ? 1.f / ds : 0.f;
        float2 o;
        o.x = A.x * inv + bias[h * 16 + 2 * fp];
        o.y = A.y * inv + bias[h * 16 + 2 * fp + 1];
        ((float2*)out)[(size_t)d * 64 + lane] = o;
    }
}

extern "C" void kernel_launch(void* const* d_in, const int* in_sizes, int n_in,
                              void* d_out, int out_size, void* d_ws, size_t ws_size,
                              hipStream_t stream)
{
    const float* feat   = (const float*)d_in[0];
    const int*   src    = (const int*)d_in[1];
    const int*   dst    = (const int*)d_in[2];
    const float* eps    = (const float*)d_in[3];
    const float* W_fc   = (const float*)d_in[4];
    const float* W_post = (const float*)d_in[5];
    const float* b_post = (const float*)d_in[6];
    const float* bias   = (const float*)d_in[7];
    float* out = (float*)d_out;

    const int N = in_sizes[0] / IN_FEAT;         // 50000
    const int E = in_sizes[1];                   // 1600000
    const int nb = (N + BNODES - 1) >> BSHIFT;   // 782 buckets

    // workspace layout (256B-aligned segments), total ~45 MB
    char* p = (char*)d_ws;
    auto alloc = [&](size_t bytes) {
        char* r = p;
        p += (bytes + 255) & ~size_t(255);
        return r;
    };
    __half* hbuf    = (__half*)alloc((size_t)N * HF * 2);     // 12.8 MB fp16
    float*  post    = (float*)alloc((size_t)N * 32 * 4);      // 6.4 MB
    int*    offsets = (int*)alloc((size_t)(N + 1) * 4);
    int*    bucket_tot    = (int*)alloc((size_t)(NBMAX + 1) * 4);
    int*    bucket_base   = (int*)alloc((size_t)(NBMAX + 1) * 4);
    int*    bucket_cursor = (int*)alloc((size_t)(NBMAX + 1) * 4);
    uint2*  recs    = (uint2*)alloc((size_t)E * 8);           // 12.8 MB
    uint2*  csr     = (uint2*)alloc((size_t)E * 8);           // 12.8 MB (edge, src)

    hipMemsetAsync(bucket_tot, 0, (size_t)(nb) * 4, stream);

    gemm_post_kernel<<<(N + 31) / 32, 256, 0, stream>>>(feat, W_fc, W_post, b_post,
                                                        hbuf, post, N);
    bucket_hist_kernel<<<512, 256, 0, stream>>>(dst, bucket_tot, E, nb);
    bucket_scan_kernel<<<1, 256, 0, stream>>>(bucket_tot, bucket_base,
                                              bucket_cursor, nb, E);
    bucket_scatter_kernel<<<(E + CHUNK - 1) / CHUNK, 256, 0, stream>>>(
        src, dst, bucket_cursor, recs, E, nb);
    bucket_csr_kernel<<<nb, 256, 0, stream>>>(recs, bucket_base, offsets, csr, N, E);
    agg_kernel<<<N, 128, 0, stream>>>(csr, offsets, post, eps, hbuf, bias, out);
}